// Round 1
// 568.211 us; speedup vs baseline: 1.0126x; 1.0126x over previous
//
#include <hip/hip_runtime.h>
#include <stdint.h>

#define B_  4
#define S_  2048
#define H_  16
#define DH_ 64
#define DM_ 1024

typedef __attribute__((ext_vector_type(8))) short bf16x8;  // 8 bf16 = 4 VGPR
typedef __attribute__((ext_vector_type(4))) float f32x4;

__device__ __forceinline__ ushort f2bf(float x){
  uint32_t u = __float_as_uint(x);
  u += 0x7FFFu + ((u >> 16) & 1u);   // RNE
  return (ushort)(u >> 16);
}
__device__ __forceinline__ uint32_t pack2(float a, float b){
  return (uint32_t)f2bf(a) | ((uint32_t)f2bf(b) << 16);
}
// truncating bf16 pack (P is in [0,1]; trunc err <= 2^-8 rel): 1 v_perm_b32
__device__ __forceinline__ uint32_t packtr(float a, float b){
  return __builtin_amdgcn_perm(__float_as_uint(b), __float_as_uint(a), 0x07060302u);
}
__device__ __forceinline__ f32x4 zero4(){ f32x4 z; z.x=0.f;z.y=0.f;z.z=0.f;z.w=0.f; return z; }

__device__ __forceinline__ void async16(void* lds, const void* g){
  __builtin_amdgcn_global_load_lds(
      (const __attribute__((address_space(1))) unsigned int*)g,
      (__attribute__((address_space(3))) unsigned int*)lds, 16, 0, 0);
}

// LDS-only barrier: waits ds ops (lgkm) but leaves global loads IN FLIGHT
// across the barrier (avoids the compiler's vmcnt(0) drain at __syncthreads,
// which was defeating every register prefetch in the attn main loop).
__device__ __forceinline__ void barrier_lgkm(){
  asm volatile("s_waitcnt lgkmcnt(0)\n\ts_barrier" ::: "memory");
}

// ---------------------------------------------------------------------------
// X fp32 -> bf16 (RNE) for xq, xk (xv is consumed fp32 by gemm_v).
// ---------------------------------------------------------------------------
__global__ __launch_bounds__(256) void conv2(const float* __restrict__ a,
                                             const float* __restrict__ b,
                                             ushort* __restrict__ oa,
                                             ushort* __restrict__ ob){
  const float* src = (blockIdx.y==0) ? a : b;
  ushort* dst      = (blockIdx.y==0) ? oa : ob;
  size_t i = ((size_t)blockIdx.x*256 + threadIdx.x)*8;   // grid covers exactly 8M
  float4 x0 = *(const float4*)&src[i];
  float4 x1 = *(const float4*)&src[i+4];
  uint4 p;
  p.x = pack2(x0.x,x0.y); p.y = pack2(x0.z,x0.w);
  p.z = pack2(x1.x,x1.y); p.w = pack2(x1.z,x1.w);
  *(uint4*)&dst[i] = p;
}

// ---------------------------------------------------------------------------
// W [K][N] fp32 -> Wt [N][K] bf16 (transpose + convert), 3 weights batched.
// ---------------------------------------------------------------------------
__global__ __launch_bounds__(256) void wtrans3(const float* __restrict__ Wq,
                                               const float* __restrict__ Wk,
                                               const float* __restrict__ Wv,
                                               ushort* __restrict__ Tq,
                                               ushort* __restrict__ Tk,
                                               ushort* __restrict__ Tv){
  const float* W = (blockIdx.z==0) ? Wq : (blockIdx.z==1) ? Wk : Wv;
  ushort* Wt     = (blockIdx.z==0) ? Tq : (blockIdx.z==1) ? Tk : Tv;
  __shared__ __align__(16) float t[32][33];
  int n0 = blockIdx.x * 32, k0 = blockIdx.y * 32;
  int col = threadIdx.x & 31, rg = threadIdx.x >> 5;
  #pragma unroll
  for (int i = 0; i < 4; i++){
    int r = rg + i*8;
    t[r][col] = W[(size_t)(k0 + r) * DM_ + n0 + col];
  }
  __syncthreads();
  #pragma unroll
  for (int i = 0; i < 4; i++){
    int r = rg + i*8;
    Wt[(size_t)(n0 + r) * DM_ + k0 + col] = f2bf(t[col][r]);
  }
}

// ---------------------------------------------------------------------------
// Q and K projection GEMMs in ONE dispatch (blockIdx.z selects), 128x128 tile,
// BK=64, both operands staged via global_load_lds w=16, XOR swizzle folded
// into the global address. D = Wt * Xb^T -> out[B,H,S,D].
// ---------------------------------------------------------------------------
__global__ __launch_bounds__(256, 4) void gemm_qk(
    const ushort* __restrict__ Xq, const ushort* __restrict__ Xk,
    const ushort* __restrict__ Wtq, const ushort* __restrict__ Wtk,
    const float* __restrict__ bq, const float* __restrict__ bk,
    ushort* __restrict__ Qo, ushort* __restrict__ Ko)
{
  const ushort* Xb = (blockIdx.z==0) ? Xq : Xk;
  const ushort* Wt = (blockIdx.z==0) ? Wtq : Wtk;
  const float* bias = (blockIdx.z==0) ? bq : bk;
  ushort* out = (blockIdx.z==0) ? Qo : Ko;

  __shared__ __align__(16) ushort lw[128*64];
  __shared__ __align__(16) ushort lx[128*64];
  int tid = threadIdx.x;
  int l = tid & 63, w = tid >> 6;
  int ln = l & 15, lq = l >> 4;
  int sbase = blockIdx.x * 128;
  int fbase = blockIdx.y * 128;
  int wm = w >> 1, wn = w & 1;

  f32x4 acc[4][4];
  #pragma unroll
  for (int i=0;i<4;i++)
    #pragma unroll
    for(int j=0;j<4;j++) acc[i][j] = zero4();

  for (int k0 = 0; k0 < DM_; k0 += 64){
    #pragma unroll
    for (int i = 0; i < 4; i++){
      int inst = w*4 + i;                 // wave-uniform LDS base
      int chunk = inst*64 + l;
      int row = chunk >> 3, slot = chunk & 7;
      int kc = slot ^ (row & 7);
      async16((char*)lw + inst*1024, &Wt[(size_t)(fbase+row)*DM_ + k0 + kc*8]);
      async16((char*)lx + inst*1024, &Xb[(size_t)(sbase+row)*DM_ + k0 + kc*8]);
    }
    __syncthreads();
    #pragma unroll
    for (int ks=0; ks<2; ks++){
      bf16x8 af[4], bfr[4];
      #pragma unroll
      for (int i=0;i<4;i++){
        int ar = wm*64 + i*16 + ln;
        int g = ks*4 + lq;
        af[i] = *(const bf16x8*)&lw[ar*64 + (g ^ (ar&7))*8];
      }
      #pragma unroll
      for (int j=0;j<4;j++){
        int br = wn*64 + j*16 + ln;
        int g = ks*4 + lq;
        bfr[j] = *(const bf16x8*)&lx[br*64 + (g ^ (br&7))*8];
      }
      #pragma unroll
      for (int i=0;i<4;i++)
        #pragma unroll
        for (int j=0;j<4;j++)
          acc[i][j] = __builtin_amdgcn_mfma_f32_16x16x32_bf16(af[i], bfr[j], acc[i][j], 0,0,0);
    }
    __syncthreads();
  }
  // D[m=feature][n=row]; col=ln -> s, row=lq*4+r -> f
  #pragma unroll
  for (int i=0;i<4;i++){
    int fr = fbase + wm*64 + i*16 + (lq<<2);
    float4 bv = *(const float4*)&bias[fr];
    int h = fr >> 6, d0 = fr & 63;
    #pragma unroll
    for (int j=0;j<4;j++){
      int s = sbase + wn*64 + j*16 + ln;
      int b = s >> 11, sq = s & 2047;
      f32x4 v = acc[i][j];
      uint2 pk;
      pk.x = pack2(v.x + bv.x, v.y + bv.y);
      pk.y = pack2(v.z + bv.z, v.w + bv.w);
      *(uint2*)&out[(((size_t)(b*H_ + h))*S_ + sq)*DH_ + d0] = pk;
    }
  }
}

// ---------------------------------------------------------------------------
// V projection: D = X * Wt^T -> Vt[B,H,D,S]. X is fp32 (VALU-converted during
// staging); Wt staged via global_load_lds.
// ---------------------------------------------------------------------------
__global__ __launch_bounds__(256, 2) void gemm_v(
    const float* __restrict__ X, const ushort* __restrict__ Wt,
    const float* __restrict__ bias, ushort* __restrict__ out)
{
  __shared__ __align__(16) ushort lw[128*64];
  __shared__ __align__(16) ushort lx[128*64];
  int tid = threadIdx.x;
  int l = tid & 63, w = tid >> 6;
  int ln = l & 15, lq = l >> 4;
  int sbase = blockIdx.x * 128;
  int fbase = blockIdx.y * 128;
  int wm = w >> 1, wn = w & 1;

  f32x4 acc[4][4];
  #pragma unroll
  for (int i=0;i<4;i++)
    #pragma unroll
    for(int j=0;j<4;j++) acc[i][j] = zero4();

  for (int k0 = 0; k0 < DM_; k0 += 64){
    #pragma unroll
    for (int i = 0; i < 4; i++){
      int inst = w*4 + i;
      int chunk = inst*64 + l;
      int row = chunk >> 3, slot = chunk & 7;
      int kc = slot ^ (row & 7);
      async16((char*)lw + inst*1024, &Wt[(size_t)(fbase+row)*DM_ + k0 + kc*8]);
    }
    #pragma unroll
    for (int r = 0; r < 4; r++){
      int flat = r*256 + tid;
      int row = flat >> 3, c = flat & 7;
      int g = c ^ (row & 7);
      const float* xs = &X[(size_t)(sbase+row)*DM_ + k0 + g*8];
      float4 x0 = *(const float4*)xs;
      float4 x1 = *(const float4*)(xs+4);
      uint4 p;
      p.x = pack2(x0.x, x0.y); p.y = pack2(x0.z, x0.w);
      p.z = pack2(x1.x, x1.y); p.w = pack2(x1.z, x1.w);
      *(uint4*)&lx[row*64 + c*8] = p;
    }
    __syncthreads();
    #pragma unroll
    for (int ks=0; ks<2; ks++){
      bf16x8 af[4], bfr[4];
      #pragma unroll
      for (int i=0;i<4;i++){
        int ar = wm*64 + i*16 + ln;
        int g = ks*4 + lq;
        af[i] = *(const bf16x8*)&lx[ar*64 + (g ^ (ar&7))*8];   // A = X rows
      }
      #pragma unroll
      for (int j=0;j<4;j++){
        int br = wn*64 + j*16 + ln;
        int g = ks*4 + lq;
        bfr[j] = *(const bf16x8*)&lw[br*64 + (g ^ (br&7))*8];  // B = W features
      }
      #pragma unroll
      for (int i=0;i<4;i++)
        #pragma unroll
        for (int j=0;j<4;j++)
          acc[i][j] = __builtin_amdgcn_mfma_f32_16x16x32_bf16(af[i], bfr[j], acc[i][j], 0,0,0);
    }
    __syncthreads();
  }
  // D[m=row][n=feature]; col=ln -> f, row=lq*4+r -> s  => Vt[b,h,d,s]
  #pragma unroll
  for (int j=0;j<4;j++){
    int fc = fbase + wn*64 + j*16 + ln;
    float bv = bias[fc];
    int h = fc >> 6, d = fc & 63;
    #pragma unroll
    for (int i=0;i<4;i++){
      int s = sbase + wm*64 + i*16 + (lq<<2);
      int b = s >> 11, sq = s & 2047;
      f32x4 v = acc[i][j];
      uint2 pk;
      pk.x = pack2(v.x + bv, v.y + bv);
      pk.y = pack2(v.z + bv, v.w + bv);
      *(uint2*)&out[(((size_t)(b*H_ + h))*DH_ + d)*S_ + sq] = pk;
    }
  }
}

// ---------------------------------------------------------------------------
// Fused attention, q-tile = 32, 1024 blocks (4/CU), wave = batch for all
// MFMA/load phases (K/V loads shared via LDS exchange, 64 B/lane/iter).
// Register prefetch: K frags for iter+1, V frags for current iter, and mask
// for iter+1 are issued right after barrier-1 and consumed a softmax+barrier
// later. Softmax over batch is elementwise in k (no online rescale).
// v2: barriers are LDS-only (barrier_lgkm) so global prefetches stay in
// flight across barriers instead of being drained by vmcnt(0) each iter;
// s_setprio(1) around MFMA clusters (T5).
// ---------------------------------------------------------------------------
__global__ __launch_bounds__(256, 4) void attn(
    const ushort* __restrict__ Q, const ushort* __restrict__ K,
    const ushort* __restrict__ Vt, const float* __restrict__ mask,
    float* __restrict__ out)
{
  __shared__ __align__(16) float  Sl[B_*32*32];   // 16 KB [b][q32][k32] swizzled
  __shared__ __align__(16) ushort Pl[B_*32*32];   // 8 KB  [b][q32][k32] linear
  int tid = threadIdx.x;
  int l = tid & 63, w = tid >> 6;        // w = batch
  int ln = l & 15, lq = l >> 4;

  // XCD grouping: 16 consecutive same-XCD slots = 16 heads sharing one q-slice
  int fid = blockIdx.x;
  int xcd = fid & 7, slot = fid >> 3;    // 128 slots per XCD
  int h = slot & 15;
  int qt = (slot >> 4) * 8 + xcd;        // 0..63
  int q0 = qt * 32;

  const ushort* Qbh = Q  + (((size_t)(w*H_ + h))*S_ + q0)*DH_;
  const ushort* Kbh = K  + ((size_t)(w*H_ + h))*S_*DH_;
  const ushort* Vbh = Vt + ((size_t)(w*H_ + h))*DH_*S_;

  // persistent Q B-frags
  bf16x8 qf[2][2];
  #pragma unroll
  for (int q2=0;q2<2;q2++)
    #pragma unroll
    for (int ks=0;ks<2;ks++)
      qf[q2][ks] = *(const bf16x8*)&Qbh[(size_t)(q2*16 + ln)*DH_ + ks*32 + lq*8];

  f32x4 of[4][2];                        // O^T accum [d-tile][q-subtile]
  #pragma unroll
  for (int i=0;i<4;i++)
    #pragma unroll
    for(int j=0;j<2;j++) of[i][j] = zero4();

  // softmax-phase identity: lane -> (q row, 4-k chunk)
  int q_sm = w*8 + (l >> 3);             // 0..31
  int kc2  = l & 7;                      // chunk of 4 k
  const float* mrow = mask + (size_t)(q0 + q_sm)*S_ + kc2*4;

  // prologue: prefetch K frags and mask for kk=0
  bf16x8 kf[2][2];
  float4 mk[4];
  #pragma unroll
  for (int t=0;t<2;t++)
    #pragma unroll
    for (int ks=0;ks<2;ks++)
      kf[t][ks] = *(const bf16x8*)&Kbh[(size_t)(t*16 + ln)*DH_ + ks*32 + lq*8];
  #pragma unroll
  for (int b2=0;b2<4;b2++)
    mk[b2] = *(const float4*)(mrow + (size_t)b2*S_*S_);

  for (int kk = 0; kk < S_; kk += 32){
    int kn = (kk + 32) & (S_ - 1);       // wrapped prefetch row (last iter harmless)

    // ---- S^T = K * Q^T (kf already in regs) ----
    f32x4 sacc[2][2];
    __builtin_amdgcn_s_setprio(1);
    #pragma unroll
    for (int t=0;t<2;t++)
      #pragma unroll
      for (int q2=0;q2<2;q2++){
        f32x4 a = __builtin_amdgcn_mfma_f32_16x16x32_bf16(kf[t][0], qf[q2][0], zero4(), 0,0,0);
        sacc[t][q2] = __builtin_amdgcn_mfma_f32_16x16x32_bf16(kf[t][1], qf[q2][1], a, 0,0,0);
      }
    __builtin_amdgcn_s_setprio(0);
    // store S^T: row q (32 floats), chunk (t*4+lq)^(q&7)  -> conflict-free
    #pragma unroll
    for (int t=0;t<2;t++)
      #pragma unroll
      for (int q2=0;q2<2;q2++){
        int q = q2*16 + ln;
        *(f32x4*)&Sl[w*1024 + q*32 + ((t*4 + lq) ^ (q & 7))*4] = sacc[t][q2];
      }
    barrier_lgkm();                      // LDS-only: K/V/mask prefetches stay in flight

    // ---- prefetch: K frags (kk+32), V frags (kk) ----
    #pragma unroll
    for (int t=0;t<2;t++)
      #pragma unroll
      for (int ks=0;ks<2;ks++)
        kf[t][ks] = *(const bf16x8*)&Kbh[(size_t)(kn + t*16 + ln)*DH_ + ks*32 + lq*8];
    bf16x8 vf[4];
    #pragma unroll
    for (int dt=0;dt<4;dt++)
      vf[dt] = *(const bf16x8*)&Vbh[(size_t)(dt*16 + ln)*S_ + kk + lq*8];

    // ---- softmax over batch (mask mk[] preloaded last iter) ----
    f32x4 sr[4];
    #pragma unroll
    for (int b2=0;b2<4;b2++)
      sr[b2] = *(const f32x4*)&Sl[b2*1024 + q_sm*32 + ((kc2) ^ (q_sm & 7))*4];
    float p[4][4];
    #pragma unroll
    for (int j=0;j<4;j++){
      float s0 = __builtin_fmaf(sr[0][j], 0.125f, __fmul_rn(((const float*)&mk[0])[j], -1e9f));
      float s1 = __builtin_fmaf(sr[1][j], 0.125f, __fmul_rn(((const float*)&mk[1])[j], -1e9f));
      float s2 = __builtin_fmaf(sr[2][j], 0.125f, __fmul_rn(((const float*)&mk[2])[j], -1e9f));
      float s3 = __builtin_fmaf(sr[3][j], 0.125f, __fmul_rn(((const float*)&mk[3])[j], -1e9f));
      float mx = fmaxf(fmaxf(s0,s1), fmaxf(s2,s3));
      float e0 = __expf(s0-mx), e1 = __expf(s1-mx);
      float e2 = __expf(s2-mx), e3 = __expf(s3-mx);
      float inv = __builtin_amdgcn_rcpf((e0+e1)+(e2+e3));
      p[0][j]=e0*inv; p[1][j]=e1*inv; p[2][j]=e2*inv; p[3][j]=e3*inv;
    }
    // prefetch mask for next iter (consumed next softmax phase)
    #pragma unroll
    for (int b2=0;b2<4;b2++)
      mk[b2] = *(const float4*)(mrow + (size_t)b2*S_*S_ + kn);
    // write P (linear layout is conflict-free for both sides)
    #pragma unroll
    for (int b2=0;b2<4;b2++){
      uint2 pk;
      pk.x = packtr(p[b2][0], p[b2][1]);
      pk.y = packtr(p[b2][2], p[b2][3]);
      *(uint2*)((char*)Pl + b2*2048 + q_sm*64 + kc2*8) = pk;
    }
    barrier_lgkm();                      // LDS-only: kf(next)/mk(next) stay in flight

    // ---- O^T += V^T * P^T (vf prefetched above) ----
    bf16x8 pf[2];
    #pragma unroll
    for (int q2=0;q2<2;q2++)
      pf[q2] = *(const bf16x8*)((char*)Pl + w*2048 + (q2*16 + ln)*64 + lq*16);
    __builtin_amdgcn_s_setprio(1);
    #pragma unroll
    for (int dt=0;dt<4;dt++)
      #pragma unroll
      for (int q2=0;q2<2;q2++)
        of[dt][q2] = __builtin_amdgcn_mfma_f32_16x16x32_bf16(vf[dt], pf[q2], of[dt][q2], 0,0,0);
    __builtin_amdgcn_s_setprio(0);
  }

  // ---- epilogue: O[b, q0+q, h*64 + d], 4 consecutive d per lane ----
  #pragma unroll
  for (int q2=0;q2<2;q2++){
    float* ob = out + ((size_t)w*S_ + q0 + q2*16 + ln)*DM_ + h*DH_;
    #pragma unroll
    for (int dt=0;dt<4;dt++)
      *(f32x4*)&ob[dt*16 + lq*4] = of[dt][q2];
  }
}

// ---------------------------------------------------------------------------
extern "C" void kernel_launch(void* const* d_in, const int* in_sizes, int n_in,
                              void* d_out, int out_size, void* d_ws, size_t ws_size,
                              hipStream_t stream)
{
  const float* xq   = (const float*)d_in[0];
  const float* xk   = (const float*)d_in[1];
  const float* xv   = (const float*)d_in[2];
  const float* mask = (const float*)d_in[3];
  const float* Wq   = (const float*)d_in[4];
  const float* bq   = (const float*)d_in[5];
  const float* Wk   = (const float*)d_in[6];
  const float* bk   = (const float*)d_in[7];
  const float* Wv   = (const float*)d_in[8];
  const float* bv   = (const float*)d_in[9];
  float* out = (float*)d_out;

  char* ws = (char*)d_ws;                      // 70 MB used
  ushort* Wtq = (ushort*)(ws);                 // 2 MB each
  ushort* Wtk = (ushort*)(ws + (2ull<<20));
  ushort* Wtv = (ushort*)(ws + (4ull<<20));
  ushort* Xbq = (ushort*)(ws + (6ull<<20));    // 16 MB each
  ushort* Xbk = (ushort*)(ws + (22ull<<20));
  ushort* Qb  = (ushort*)(ws + (38ull<<20));
  ushort* Kb  = (ushort*)(ws + (54ull<<20));
  ushort* Vtb = Xbq;                           // safe: Xbq consumed by gemm_qk before gemm_v runs

  conv2<<<dim3(4096,2), 256, 0, stream>>>(xq, xk, Xbq, Xbk);
  wtrans3<<<dim3(32,32,3), 256, 0, stream>>>(Wq, Wk, Wv, Wtq, Wtk, Wtv);

  gemm_qk<<<dim3(64,8,2), 256, 0, stream>>>(Xbq, Xbk, Wtq, Wtk, bq, bk, Qb, Kb);
  gemm_v<<<dim3(64,8), 256, 0, stream>>>(xv, Wtv, bv, Vtb);

  attn<<<1024, 256, 0, stream>>>(Qb, Kb, Vtb, mask, out);
}

// Round 2
// 476.810 us; speedup vs baseline: 1.2067x; 1.1917x over previous
//
#include <hip/hip_runtime.h>
#include <stdint.h>

#define B_  4
#define S_  2048
#define H_  16
#define DH_ 64
#define DM_ 1024

typedef __attribute__((ext_vector_type(8))) short bf16x8;  // 8 bf16 = 4 VGPR
typedef __attribute__((ext_vector_type(4))) short bf16x4;  // 4 bf16 = 2 VGPR
typedef __attribute__((ext_vector_type(4))) float f32x4;

__device__ __forceinline__ ushort f2bf(float x){
  uint32_t u = __float_as_uint(x);
  u += 0x7FFFu + ((u >> 16) & 1u);   // RNE
  return (ushort)(u >> 16);
}
__device__ __forceinline__ uint32_t pack2(float a, float b){
  return (uint32_t)f2bf(a) | ((uint32_t)f2bf(b) << 16);
}
// truncating bf16 pack (P is in [0,1]; trunc err <= 2^-8 rel): 1 v_perm_b32
__device__ __forceinline__ uint32_t packtr(float a, float b){
  return __builtin_amdgcn_perm(__float_as_uint(b), __float_as_uint(a), 0x07060302u);
}
__device__ __forceinline__ f32x4 zero4(){ f32x4 z; z.x=0.f;z.y=0.f;z.z=0.f;z.w=0.f; return z; }

__device__ __forceinline__ void async16(void* lds, const void* g){
  __builtin_amdgcn_global_load_lds(
      (const __attribute__((address_space(1))) unsigned int*)g,
      (__attribute__((address_space(3))) unsigned int*)lds, 16, 0, 0);
}

// hardware 2^x
__device__ __forceinline__ float exp2_hw(float x){
#if __has_builtin(__builtin_amdgcn_exp2f)
  return __builtin_amdgcn_exp2f(x);
#else
  float r; asm("v_exp_f32 %0, %1" : "=v"(r) : "v"(x)); return r;
#endif
}

// 16x16x16 bf16 MFMA (K=16): builtin if present, else raw encoding
__device__ __forceinline__ f32x4 mfma16(bf16x4 a, bf16x4 b, f32x4 c){
#if __has_builtin(__builtin_amdgcn_mfma_f32_16x16x16bf16_1k)
  return __builtin_amdgcn_mfma_f32_16x16x16bf16_1k(a, b, c, 0, 0, 0);
#elif __has_builtin(__builtin_amdgcn_mfma_f32_16x16x16_bf16)
  return __builtin_amdgcn_mfma_f32_16x16x16_bf16(a, b, c, 0, 0, 0);
#else
  f32x4 d = c;
  asm("v_mfma_f32_16x16x16_bf16 %0, %1, %2, %0" : "+v"(d) : "v"(a), "v"(b));
  return d;
#endif
}

// ---------------------------------------------------------------------------
// X fp32 -> bf16 (RNE) for xq, xk (xv is consumed fp32 by gemm_v).
// ---------------------------------------------------------------------------
__global__ __launch_bounds__(256) void conv2(const float* __restrict__ a,
                                             const float* __restrict__ b,
                                             ushort* __restrict__ oa,
                                             ushort* __restrict__ ob){
  const float* src = (blockIdx.y==0) ? a : b;
  ushort* dst      = (blockIdx.y==0) ? oa : ob;
  size_t i = ((size_t)blockIdx.x*256 + threadIdx.x)*8;   // grid covers exactly 8M
  float4 x0 = *(const float4*)&src[i];
  float4 x1 = *(const float4*)&src[i+4];
  uint4 p;
  p.x = pack2(x0.x,x0.y); p.y = pack2(x0.z,x0.w);
  p.z = pack2(x1.x,x1.y); p.w = pack2(x1.z,x1.w);
  *(uint4*)&dst[i] = p;
}

// ---------------------------------------------------------------------------
// W [K][N] fp32 -> Wt [N][K] bf16 (transpose + convert), 3 weights batched.
// ---------------------------------------------------------------------------
__global__ __launch_bounds__(256) void wtrans3(const float* __restrict__ Wq,
                                               const float* __restrict__ Wk,
                                               const float* __restrict__ Wv,
                                               ushort* __restrict__ Tq,
                                               ushort* __restrict__ Tk,
                                               ushort* __restrict__ Tv){
  const float* W = (blockIdx.z==0) ? Wq : (blockIdx.z==1) ? Wk : Wv;
  ushort* Wt     = (blockIdx.z==0) ? Tq : (blockIdx.z==1) ? Tk : Tv;
  __shared__ __align__(16) float t[32][33];
  int n0 = blockIdx.x * 32, k0 = blockIdx.y * 32;
  int col = threadIdx.x & 31, rg = threadIdx.x >> 5;
  #pragma unroll
  for (int i = 0; i < 4; i++){
    int r = rg + i*8;
    t[r][col] = W[(size_t)(k0 + r) * DM_ + n0 + col];
  }
  __syncthreads();
  #pragma unroll
  for (int i = 0; i < 4; i++){
    int r = rg + i*8;
    Wt[(size_t)(n0 + r) * DM_ + k0 + col] = f2bf(t[col][r]);
  }
}

// ---------------------------------------------------------------------------
// Q and K projection GEMMs in ONE dispatch (blockIdx.z selects), 128x128 tile,
// BK=64, both operands staged via global_load_lds w=16, XOR swizzle folded
// into the global address. D = Wt * Xb^T -> out[B,H,S,D].
// ---------------------------------------------------------------------------
__global__ __launch_bounds__(256, 4) void gemm_qk(
    const ushort* __restrict__ Xq, const ushort* __restrict__ Xk,
    const ushort* __restrict__ Wtq, const ushort* __restrict__ Wtk,
    const float* __restrict__ bq, const float* __restrict__ bk,
    ushort* __restrict__ Qo, ushort* __restrict__ Ko)
{
  const ushort* Xb = (blockIdx.z==0) ? Xq : Xk;
  const ushort* Wt = (blockIdx.z==0) ? Wtq : Wtk;
  const float* bias = (blockIdx.z==0) ? bq : bk;
  ushort* out = (blockIdx.z==0) ? Qo : Ko;

  __shared__ __align__(16) ushort lw[128*64];
  __shared__ __align__(16) ushort lx[128*64];
  int tid = threadIdx.x;
  int l = tid & 63, w = tid >> 6;
  int ln = l & 15, lq = l >> 4;
  int sbase = blockIdx.x * 128;
  int fbase = blockIdx.y * 128;
  int wm = w >> 1, wn = w & 1;

  f32x4 acc[4][4];
  #pragma unroll
  for (int i=0;i<4;i++)
    #pragma unroll
    for(int j=0;j<4;j++) acc[i][j] = zero4();

  for (int k0 = 0; k0 < DM_; k0 += 64){
    #pragma unroll
    for (int i = 0; i < 4; i++){
      int inst = w*4 + i;                 // wave-uniform LDS base
      int chunk = inst*64 + l;
      int row = chunk >> 3, slot = chunk & 7;
      int kc = slot ^ (row & 7);
      async16((char*)lw + inst*1024, &Wt[(size_t)(fbase+row)*DM_ + k0 + kc*8]);
      async16((char*)lx + inst*1024, &Xb[(size_t)(sbase+row)*DM_ + k0 + kc*8]);
    }
    __syncthreads();
    #pragma unroll
    for (int ks=0; ks<2; ks++){
      bf16x8 af[4], bfr[4];
      #pragma unroll
      for (int i=0;i<4;i++){
        int ar = wm*64 + i*16 + ln;
        int g = ks*4 + lq;
        af[i] = *(const bf16x8*)&lw[ar*64 + (g ^ (ar&7))*8];
      }
      #pragma unroll
      for (int j=0;j<4;j++){
        int br = wn*64 + j*16 + ln;
        int g = ks*4 + lq;
        bfr[j] = *(const bf16x8*)&lx[br*64 + (g ^ (br&7))*8];
      }
      #pragma unroll
      for (int i=0;i<4;i++)
        #pragma unroll
        for (int j=0;j<4;j++)
          acc[i][j] = __builtin_amdgcn_mfma_f32_16x16x32_bf16(af[i], bfr[j], acc[i][j], 0,0,0);
    }
    __syncthreads();
  }
  // D[m=feature][n=row]; col=ln -> s, row=lq*4+r -> f
  #pragma unroll
  for (int i=0;i<4;i++){
    int fr = fbase + wm*64 + i*16 + (lq<<2);
    float4 bv = *(const float4*)&bias[fr];
    int h = fr >> 6, d0 = fr & 63;
    #pragma unroll
    for (int j=0;j<4;j++){
      int s = sbase + wn*64 + j*16 + ln;
      int b = s >> 11, sq = s & 2047;
      f32x4 v = acc[i][j];
      uint2 pk;
      pk.x = pack2(v.x + bv.x, v.y + bv.y);
      pk.y = pack2(v.z + bv.z, v.w + bv.w);
      *(uint2*)&out[(((size_t)(b*H_ + h))*S_ + sq)*DH_ + d0] = pk;
    }
  }
}

// ---------------------------------------------------------------------------
// V projection: D = X * Wt^T -> Vt[B,H,D,S]. X is fp32 (VALU-converted during
// staging); Wt staged via global_load_lds.
// ---------------------------------------------------------------------------
__global__ __launch_bounds__(256, 2) void gemm_v(
    const float* __restrict__ X, const ushort* __restrict__ Wt,
    const float* __restrict__ bias, ushort* __restrict__ out)
{
  __shared__ __align__(16) ushort lw[128*64];
  __shared__ __align__(16) ushort lx[128*64];
  int tid = threadIdx.x;
  int l = tid & 63, w = tid >> 6;
  int ln = l & 15, lq = l >> 4;
  int sbase = blockIdx.x * 128;
  int fbase = blockIdx.y * 128;
  int wm = w >> 1, wn = w & 1;

  f32x4 acc[4][4];
  #pragma unroll
  for (int i=0;i<4;i++)
    #pragma unroll
    for(int j=0;j<4;j++) acc[i][j] = zero4();

  for (int k0 = 0; k0 < DM_; k0 += 64){
    #pragma unroll
    for (int i = 0; i < 4; i++){
      int inst = w*4 + i;
      int chunk = inst*64 + l;
      int row = chunk >> 3, slot = chunk & 7;
      int kc = slot ^ (row & 7);
      async16((char*)lw + inst*1024, &Wt[(size_t)(fbase+row)*DM_ + k0 + kc*8]);
    }
    #pragma unroll
    for (int r = 0; r < 4; r++){
      int flat = r*256 + tid;
      int row = flat >> 3, c = flat & 7;
      int g = c ^ (row & 7);
      const float* xs = &X[(size_t)(sbase+row)*DM_ + k0 + g*8];
      float4 x0 = *(const float4*)xs;
      float4 x1 = *(const float4*)(xs+4);
      uint4 p;
      p.x = pack2(x0.x, x0.y); p.y = pack2(x0.z, x0.w);
      p.z = pack2(x1.x, x1.y); p.w = pack2(x1.z, x1.w);
      *(uint4*)&lx[row*64 + c*8] = p;
    }
    __syncthreads();
    #pragma unroll
    for (int ks=0; ks<2; ks++){
      bf16x8 af[4], bfr[4];
      #pragma unroll
      for (int i=0;i<4;i++){
        int ar = wm*64 + i*16 + ln;
        int g = ks*4 + lq;
        af[i] = *(const bf16x8*)&lx[ar*64 + (g ^ (ar&7))*8];   // A = X rows
      }
      #pragma unroll
      for (int j=0;j<4;j++){
        int br = wn*64 + j*16 + ln;
        int g = ks*4 + lq;
        bfr[j] = *(const bf16x8*)&lw[br*64 + (g ^ (br&7))*8];  // B = W features
      }
      #pragma unroll
      for (int i=0;i<4;i++)
        #pragma unroll
        for (int j=0;j<4;j++)
          acc[i][j] = __builtin_amdgcn_mfma_f32_16x16x32_bf16(af[i], bfr[j], acc[i][j], 0,0,0);
    }
    __syncthreads();
  }
  // D[m=row][n=feature]; col=ln -> f, row=lq*4+r -> s  => Vt[b,h,d,s]
  #pragma unroll
  for (int j=0;j<4;j++){
    int fc = fbase + wn*64 + j*16 + ln;
    float bv = bias[fc];
    int h = fc >> 6, d = fc & 63;
    #pragma unroll
    for (int i=0;i<4;i++){
      int s = sbase + wm*64 + i*16 + (lq<<2);
      int b = s >> 11, sq = s & 2047;
      f32x4 v = acc[i][j];
      uint2 pk;
      pk.x = pack2(v.x + bv, v.y + bv);
      pk.y = pack2(v.z + bv, v.w + bv);
      *(uint2*)&out[(((size_t)(b*H_ + h))*DH_ + d)*S_ + sq] = pk;
    }
  }
}

// ---------------------------------------------------------------------------
// Fused attention v3: batch-in-lane decomposition.
// Softmax is over the BATCH axis only (no k-reduction), so one wave holds all
// 4 batches of the same (q,k) tile: the QK^T C-layout (k=lq*4+r, q=ln) is
// per-lane identical across batches -> softmax is pure register math, and it
// EXACTLY matches the 16x16x16 PV A/B operand layout (k=lq*4+e) -> zero
// cross-lane exchange, zero S/P LDS, zero exchange barriers.
// Block = 4 waves = same head h, 4 adjacent 16-row q-tiles; K/V tiles (k16)
// are staged once per block via global_load_lds double-buffer (counted
// vmcnt(4), one barrier/iter). Mask is loaded per-lane, prefetched 1 iter.
// Grid 512 blocks -> bid%8 == h%8 pins each head's K/V stream to one XCD L2.
// ---------------------------------------------------------------------------
#define CS_LOG2 0.18033688011112042f      /* 0.125 * log2(e) */
#define CM_LOG2 -1.4426950408889634e9f    /* -1e9 * log2(e) */

__global__ __launch_bounds__(256, 2) void attn(
    const ushort* __restrict__ Q, const ushort* __restrict__ K,
    const ushort* __restrict__ Vt, const float* __restrict__ mask,
    float* __restrict__ out)
{
  __shared__ __align__(16) ushort Kl[2][4096];   // [buf][b*1024 + r*64 + c] (c XOR-swizzled)
  __shared__ __align__(16) ushort Vl[2][4096];   // [buf][b*1024 + d*16 + k] linear

  const int tid = threadIdx.x;
  const int l = tid & 63, w = tid >> 6;
  const int ln = l & 15, lq = l >> 4;
  const int bid = blockIdx.x;
  const int h = bid & 15, qtg = bid >> 4;
  const int q0 = (qtg*4 + w)*16;

  const ushort* Kroot = K  + (size_t)h*S_*DH_;
  const ushort* Vroot = Vt + (size_t)h*DH_*S_;

  // per-lane stage source offsets (elements); inst = w*2+j covers 0..7
  uint ksrc[2], vsrc[2];
  int kdst[2], vdst[2];
  #pragma unroll
  for (int j=0;j<2;j++){
    int inst = w*2 + j;
    int cc = inst*64 + l;
    { int b = cc>>7, r = (cc>>3)&15, c = cc&7;
      ksrc[j] = (uint)(b*(H_*S_*DH_) + r*DH_ + (c ^ (r&7))*8);
      kdst[j] = inst*512; }
    { int b = cc>>7, rem = cc&127, r = rem>>1, c = rem&1;
      vsrc[j] = (uint)(b*(H_*DH_*S_) + r*S_ + c*8);
      vdst[j] = inst*512; }
  }

  // persistent Q fragments (all 4 batches)
  bf16x8 qf[4][2];
  #pragma unroll
  for (int b=0;b<4;b++){
    const ushort* Qb = Q + (((size_t)(b*H_ + h))*S_ + q0 + ln)*DH_;
    #pragma unroll
    for (int ks=0;ks<2;ks++)
      qf[b][ks] = *(const bf16x8*)&Qb[ks*32 + lq*8];
  }

  f32x4 of[4][4];                        // [batch][d-tile] accumulators
  #pragma unroll
  for (int b=0;b<4;b++)
    #pragma unroll
    for (int dt=0;dt<4;dt++) of[b][dt] = zero4();

  const uint moff = (uint)((q0 + ln)*S_ + lq*4);   // mask lane offset (elements)

  // prologue: stage buf0 (kk=0), prefetch mask(kk=0)
  #pragma unroll
  for (int j=0;j<2;j++){
    async16(&Kl[0][kdst[j]], Kroot + ksrc[j]);
    async16(&Vl[0][vdst[j]], Vroot + vsrc[j]);
  }
  __builtin_amdgcn_sched_barrier(0);
  f32x4 mk[4];
  #pragma unroll
  for (int b=0;b<4;b++)
    mk[b] = *(const f32x4*)&mask[(size_t)b*S_*S_ + moff];
  asm volatile("s_waitcnt vmcnt(4)\n\ts_barrier" ::: "memory");

#define ATTN_ITER(CUR, KKV)                                                     \
  {                                                                             \
    const int kk_ = (KKV);                                                      \
    const int kn_ = (kk_ + 16) & (S_ - 1);                                      \
    /* stage next tile into buf^1 (4 instrs/wave, oldest vmem of the iter) */   \
    _Pragma("unroll")                                                           \
    for (int j=0;j<2;j++){                                                      \
      async16(&Kl[(CUR)^1][kdst[j]], Kroot + ksrc[j] + (uint)kn_*DH_);          \
      async16(&Vl[(CUR)^1][vdst[j]], Vroot + vsrc[j] + (uint)kn_);              \
    }                                                                           \
    __builtin_amdgcn_sched_barrier(0);                                          \
    /* fragments from current buffer */                                         \
    bf16x8 kf[4][2];                                                            \
    _Pragma("unroll")                                                           \
    for (int b=0;b<4;b++)                                                       \
      _Pragma("unroll")                                                         \
      for (int ks=0;ks<2;ks++)                                                  \
        kf[b][ks] = *(const bf16x8*)&Kl[CUR][b*1024 + ln*64 + ((ks*4+lq) ^ (ln&7))*8]; \
    bf16x4 vf[4][4];                                                            \
    _Pragma("unroll")                                                           \
    for (int b=0;b<4;b++)                                                       \
      _Pragma("unroll")                                                         \
      for (int dt=0;dt<4;dt++)                                                  \
        vf[b][dt] = *(const bf16x4*)&Vl[CUR][b*1024 + (dt*16+ln)*16 + lq*4];    \
    /* S^T = K * Q^T : lane holds s[b] at (k = kk+lq*4+r, q = q0+ln) */         \
    f32x4 sacc[4];                                                              \
    __builtin_amdgcn_s_setprio(1);                                              \
    _Pragma("unroll")                                                           \
    for (int b=0;b<4;b++){                                                      \
      f32x4 a_ = __builtin_amdgcn_mfma_f32_16x16x32_bf16(kf[b][0], qf[b][0], zero4(), 0,0,0); \
      sacc[b]  = __builtin_amdgcn_mfma_f32_16x16x32_bf16(kf[b][1], qf[b][1], a_, 0,0,0); \
    }                                                                           \
    __builtin_amdgcn_s_setprio(0);                                              \
    /* softmax over batch, log2 domain, pure per-lane */                        \
    float pw[4][4];                                                             \
    _Pragma("unroll")                                                           \
    for (int j=0;j<4;j++){                                                      \
      float s0 = __builtin_fmaf(sacc[0][j], CS_LOG2, mk[0][j]*CM_LOG2);         \
      float s1 = __builtin_fmaf(sacc[1][j], CS_LOG2, mk[1][j]*CM_LOG2);         \
      float s2 = __builtin_fmaf(sacc[2][j], CS_LOG2, mk[2][j]*CM_LOG2);         \
      float s3 = __builtin_fmaf(sacc[3][j], CS_LOG2, mk[3][j]*CM_LOG2);         \
      float mx = fmaxf(fmaxf(s0,s1), fmaxf(s2,s3));                             \
      float e0 = exp2_hw(s0-mx), e1 = exp2_hw(s1-mx);                           \
      float e2 = exp2_hw(s2-mx), e3 = exp2_hw(s3-mx);                           \
      float inv = __builtin_amdgcn_rcpf((e0+e1)+(e2+e3));                       \
      pw[0][j]=e0*inv; pw[1][j]=e1*inv; pw[2][j]=e2*inv; pw[3][j]=e3*inv;       \
    }                                                                           \
    /* prefetch mask for next iter (after last mk use; stays newest in vmem) */ \
    _Pragma("unroll")                                                           \
    for (int b=0;b<4;b++)                                                       \
      mk[b] = *(const f32x4*)&mask[(size_t)b*S_*S_ + moff + (uint)kn_];         \
    /* pack P into 16x16x16 operand layout (k = lq*4 + e, q = ln) */            \
    bf16x4 pf[4];                                                               \
    _Pragma("unroll")                                                           \
    for (int b=0;b<4;b++){                                                      \
      uint2 up;                                                                 \
      up.x = packtr(pw[b][0], pw[b][1]);                                        \
      up.y = packtr(pw[b][2], pw[b][3]);                                        \
      pf[b] = __builtin_bit_cast(bf16x4, up);                                   \
    }                                                                           \
    /* O^T += V^T * P^T */                                                      \
    __builtin_amdgcn_s_setprio(1);                                              \
    _Pragma("unroll")                                                           \
    for (int b=0;b<4;b++)                                                       \
      _Pragma("unroll")                                                         \
      for (int dt=0;dt<4;dt++)                                                  \
        of[b][dt] = mfma16(vf[b][dt], pf[b], of[b][dt]);                        \
    __builtin_amdgcn_s_setprio(0);                                              \
    /* drain my 4 stage loads (oldest); leave 4 mask loads in flight */         \
    asm volatile("s_waitcnt vmcnt(4)\n\ts_barrier" ::: "memory");               \
  }

  #pragma unroll 1
  for (int kk = 0; kk < S_; kk += 32){
    ATTN_ITER(0, kk);
    ATTN_ITER(1, kk+16);
  }
#undef ATTN_ITER

  // epilogue: O[b, q0+ln, h*64 + dt*16 + lq*4 + r]
  #pragma unroll
  for (int b=0;b<4;b++){
    float* ob = out + ((size_t)b*S_ + q0 + ln)*DM_ + h*DH_;
    #pragma unroll
    for (int dt=0;dt<4;dt++)
      *(f32x4*)&ob[dt*16 + lq*4] = of[b][dt];
  }
}

// ---------------------------------------------------------------------------
extern "C" void kernel_launch(void* const* d_in, const int* in_sizes, int n_in,
                              void* d_out, int out_size, void* d_ws, size_t ws_size,
                              hipStream_t stream)
{
  const float* xq   = (const float*)d_in[0];
  const float* xk   = (const float*)d_in[1];
  const float* xv   = (const float*)d_in[2];
  const float* mask = (const float*)d_in[3];
  const float* Wq   = (const float*)d_in[4];
  const float* bq   = (const float*)d_in[5];
  const float* Wk   = (const float*)d_in[6];
  const float* bk   = (const float*)d_in[7];
  const float* Wv   = (const float*)d_in[8];
  const float* bv   = (const float*)d_in[9];
  float* out = (float*)d_out;

  char* ws = (char*)d_ws;                      // 70 MB used
  ushort* Wtq = (ushort*)(ws);                 // 2 MB each
  ushort* Wtk = (ushort*)(ws + (2ull<<20));
  ushort* Wtv = (ushort*)(ws + (4ull<<20));
  ushort* Xbq = (ushort*)(ws + (6ull<<20));    // 16 MB each
  ushort* Xbk = (ushort*)(ws + (22ull<<20));
  ushort* Qb  = (ushort*)(ws + (38ull<<20));
  ushort* Kb  = (ushort*)(ws + (54ull<<20));
  ushort* Vtb = Xbq;                           // safe: Xbq consumed by gemm_qk before gemm_v runs

  conv2<<<dim3(4096,2), 256, 0, stream>>>(xq, xk, Xbq, Xbk);
  wtrans3<<<dim3(32,32,3), 256, 0, stream>>>(Wq, Wk, Wv, Wtq, Wtk, Wtv);

  gemm_qk<<<dim3(64,8,2), 256, 0, stream>>>(Xbq, Xbk, Wtq, Wtk, bq, bk, Qb, Kb);
  gemm_v<<<dim3(64,8), 256, 0, stream>>>(xv, Wtv, bv, Vtb);

  attn<<<512, 256, 0, stream>>>(Qb, Kb, Vtb, mask, out);
}

// Round 3
// 452.151 us; speedup vs baseline: 1.2726x; 1.0545x over previous
//
#include <hip/hip_runtime.h>
#include <stdint.h>

#define B_  4
#define S_  2048
#define H_  16
#define DH_ 64
#define DM_ 1024

typedef __attribute__((ext_vector_type(8))) short bf16x8;  // 8 bf16 = 4 VGPR
typedef __attribute__((ext_vector_type(4))) float f32x4;

__device__ __forceinline__ ushort f2bf(float x){
  uint32_t u = __float_as_uint(x);
  u += 0x7FFFu + ((u >> 16) & 1u);   // RNE
  return (ushort)(u >> 16);
}
__device__ __forceinline__ uint32_t pack2(float a, float b){
  return (uint32_t)f2bf(a) | ((uint32_t)f2bf(b) << 16);
}
// truncating bf16 pack (P is in [0,1]; trunc err <= 2^-8 rel): 1 v_perm_b32
__device__ __forceinline__ uint32_t packtr(float a, float b){
  return __builtin_amdgcn_perm(__float_as_uint(b), __float_as_uint(a), 0x07060302u);
}
__device__ __forceinline__ f32x4 zero4(){ f32x4 z; z.x=0.f;z.y=0.f;z.z=0.f;z.w=0.f; return z; }

__device__ __forceinline__ void async16(void* lds, const void* g){
  __builtin_amdgcn_global_load_lds(
      (const __attribute__((address_space(1))) unsigned int*)g,
      (__attribute__((address_space(3))) unsigned int*)lds, 16, 0, 0);
}

// hardware 2^x
__device__ __forceinline__ float exp2_hw(float x){
#if __has_builtin(__builtin_amdgcn_exp2f)
  return __builtin_amdgcn_exp2f(x);
#else
  float r; asm("v_exp_f32 %0, %1" : "=v"(r) : "v"(x)); return r;
#endif
}

// ---------------------------------------------------------------------------
// X fp32 -> bf16 (RNE) for xq, xk (xv is consumed fp32 by gemm_v).
// ---------------------------------------------------------------------------
__global__ __launch_bounds__(256) void conv2(const float* __restrict__ a,
                                             const float* __restrict__ b,
                                             ushort* __restrict__ oa,
                                             ushort* __restrict__ ob){
  const float* src = (blockIdx.y==0) ? a : b;
  ushort* dst      = (blockIdx.y==0) ? oa : ob;
  size_t i = ((size_t)blockIdx.x*256 + threadIdx.x)*8;   // grid covers exactly 8M
  float4 x0 = *(const float4*)&src[i];
  float4 x1 = *(const float4*)&src[i+4];
  uint4 p;
  p.x = pack2(x0.x,x0.y); p.y = pack2(x0.z,x0.w);
  p.z = pack2(x1.x,x1.y); p.w = pack2(x1.z,x1.w);
  *(uint4*)&dst[i] = p;
}

// ---------------------------------------------------------------------------
// W [K][N] fp32 -> Wt [N][K] bf16 (transpose + convert), 3 weights batched.
// ---------------------------------------------------------------------------
__global__ __launch_bounds__(256) void wtrans3(const float* __restrict__ Wq,
                                               const float* __restrict__ Wk,
                                               const float* __restrict__ Wv,
                                               ushort* __restrict__ Tq,
                                               ushort* __restrict__ Tk,
                                               ushort* __restrict__ Tv){
  const float* W = (blockIdx.z==0) ? Wq : (blockIdx.z==1) ? Wk : Wv;
  ushort* Wt     = (blockIdx.z==0) ? Tq : (blockIdx.z==1) ? Tk : Tv;
  __shared__ __align__(16) float t[32][33];
  int n0 = blockIdx.x * 32, k0 = blockIdx.y * 32;
  int col = threadIdx.x & 31, rg = threadIdx.x >> 5;
  #pragma unroll
  for (int i = 0; i < 4; i++){
    int r = rg + i*8;
    t[r][col] = W[(size_t)(k0 + r) * DM_ + n0 + col];
  }
  __syncthreads();
  #pragma unroll
  for (int i = 0; i < 4; i++){
    int r = rg + i*8;
    Wt[(size_t)(n0 + r) * DM_ + k0 + col] = f2bf(t[col][r]);
  }
}

// ---------------------------------------------------------------------------
// Q and K projection GEMMs in ONE dispatch (blockIdx.z selects), 128x128 tile,
// BK=64, both operands staged via global_load_lds w=16, XOR swizzle folded
// into the global address. D = Wt * Xb^T -> out[B,H,S,D].
// ---------------------------------------------------------------------------
__global__ __launch_bounds__(256, 4) void gemm_qk(
    const ushort* __restrict__ Xq, const ushort* __restrict__ Xk,
    const ushort* __restrict__ Wtq, const ushort* __restrict__ Wtk,
    const float* __restrict__ bq, const float* __restrict__ bk,
    ushort* __restrict__ Qo, ushort* __restrict__ Ko)
{
  const ushort* Xb = (blockIdx.z==0) ? Xq : Xk;
  const ushort* Wt = (blockIdx.z==0) ? Wtq : Wtk;
  const float* bias = (blockIdx.z==0) ? bq : bk;
  ushort* out = (blockIdx.z==0) ? Qo : Ko;

  __shared__ __align__(16) ushort lw[128*64];
  __shared__ __align__(16) ushort lx[128*64];
  int tid = threadIdx.x;
  int l = tid & 63, w = tid >> 6;
  int ln = l & 15, lq = l >> 4;
  int sbase = blockIdx.x * 128;
  int fbase = blockIdx.y * 128;
  int wm = w >> 1, wn = w & 1;

  f32x4 acc[4][4];
  #pragma unroll
  for (int i=0;i<4;i++)
    #pragma unroll
    for(int j=0;j<4;j++) acc[i][j] = zero4();

  for (int k0 = 0; k0 < DM_; k0 += 64){
    #pragma unroll
    for (int i = 0; i < 4; i++){
      int inst = w*4 + i;                 // wave-uniform LDS base
      int chunk = inst*64 + l;
      int row = chunk >> 3, slot = chunk & 7;
      int kc = slot ^ (row & 7);
      async16((char*)lw + inst*1024, &Wt[(size_t)(fbase+row)*DM_ + k0 + kc*8]);
      async16((char*)lx + inst*1024, &Xb[(size_t)(sbase+row)*DM_ + k0 + kc*8]);
    }
    __syncthreads();
    #pragma unroll
    for (int ks=0; ks<2; ks++){
      bf16x8 af[4], bfr[4];
      #pragma unroll
      for (int i=0;i<4;i++){
        int ar = wm*64 + i*16 + ln;
        int g = ks*4 + lq;
        af[i] = *(const bf16x8*)&lw[ar*64 + (g ^ (ar&7))*8];
      }
      #pragma unroll
      for (int j=0;j<4;j++){
        int br = wn*64 + j*16 + ln;
        int g = ks*4 + lq;
        bfr[j] = *(const bf16x8*)&lx[br*64 + (g ^ (br&7))*8];
      }
      #pragma unroll
      for (int i=0;i<4;i++)
        #pragma unroll
        for (int j=0;j<4;j++)
          acc[i][j] = __builtin_amdgcn_mfma_f32_16x16x32_bf16(af[i], bfr[j], acc[i][j], 0,0,0);
    }
    __syncthreads();
  }
  // D[m=feature][n=row]; col=ln -> s, row=lq*4+r -> f
  #pragma unroll
  for (int i=0;i<4;i++){
    int fr = fbase + wm*64 + i*16 + (lq<<2);
    float4 bv = *(const float4*)&bias[fr];
    int h = fr >> 6, d0 = fr & 63;
    #pragma unroll
    for (int j=0;j<4;j++){
      int s = sbase + wn*64 + j*16 + ln;
      int b = s >> 11, sq = s & 2047;
      f32x4 v = acc[i][j];
      uint2 pk;
      pk.x = pack2(v.x + bv.x, v.y + bv.y);
      pk.y = pack2(v.z + bv.z, v.w + bv.w);
      *(uint2*)&out[(((size_t)(b*H_ + h))*S_ + sq)*DH_ + d0] = pk;
    }
  }
}

// ---------------------------------------------------------------------------
// V projection: D = X * Wt^T -> Vt[B,H,D,S]. X is fp32 (VALU-converted during
// staging); Wt staged via global_load_lds.
// ---------------------------------------------------------------------------
__global__ __launch_bounds__(256, 2) void gemm_v(
    const float* __restrict__ X, const ushort* __restrict__ Wt,
    const float* __restrict__ bias, ushort* __restrict__ out)
{
  __shared__ __align__(16) ushort lw[128*64];
  __shared__ __align__(16) ushort lx[128*64];
  int tid = threadIdx.x;
  int l = tid & 63, w = tid >> 6;
  int ln = l & 15, lq = l >> 4;
  int sbase = blockIdx.x * 128;
  int fbase = blockIdx.y * 128;
  int wm = w >> 1, wn = w & 1;

  f32x4 acc[4][4];
  #pragma unroll
  for (int i=0;i<4;i++)
    #pragma unroll
    for(int j=0;j<4;j++) acc[i][j] = zero4();

  for (int k0 = 0; k0 < DM_; k0 += 64){
    #pragma unroll
    for (int i = 0; i < 4; i++){
      int inst = w*4 + i;
      int chunk = inst*64 + l;
      int row = chunk >> 3, slot = chunk & 7;
      int kc = slot ^ (row & 7);
      async16((char*)lw + inst*1024, &Wt[(size_t)(fbase+row)*DM_ + k0 + kc*8]);
    }
    #pragma unroll
    for (int r = 0; r < 4; r++){
      int flat = r*256 + tid;
      int row = flat >> 3, c = flat & 7;
      int g = c ^ (row & 7);
      const float* xs = &X[(size_t)(sbase+row)*DM_ + k0 + g*8];
      float4 x0 = *(const float4*)xs;
      float4 x1 = *(const float4*)(xs+4);
      uint4 p;
      p.x = pack2(x0.x, x0.y); p.y = pack2(x0.z, x0.w);
      p.z = pack2(x1.x, x1.y); p.w = pack2(x1.z, x1.w);
      *(uint4*)&lx[row*64 + c*8] = p;
    }
    __syncthreads();
    #pragma unroll
    for (int ks=0; ks<2; ks++){
      bf16x8 af[4], bfr[4];
      #pragma unroll
      for (int i=0;i<4;i++){
        int ar = wm*64 + i*16 + ln;
        int g = ks*4 + lq;
        af[i] = *(const bf16x8*)&lx[ar*64 + (g ^ (ar&7))*8];   // A = X rows
      }
      #pragma unroll
      for (int j=0;j<4;j++){
        int br = wn*64 + j*16 + ln;
        int g = ks*4 + lq;
        bfr[j] = *(const bf16x8*)&lw[br*64 + (g ^ (br&7))*8];  // B = W features
      }
      #pragma unroll
      for (int i=0;i<4;i++)
        #pragma unroll
        for (int j=0;j<4;j++)
          acc[i][j] = __builtin_amdgcn_mfma_f32_16x16x32_bf16(af[i], bfr[j], acc[i][j], 0,0,0);
    }
    __syncthreads();
  }
  // D[m=row][n=feature]; col=ln -> f, row=lq*4+r -> s  => Vt[b,h,d,s]
  #pragma unroll
  for (int j=0;j<4;j++){
    int fc = fbase + wn*64 + j*16 + ln;
    float bv = bias[fc];
    int h = fc >> 6, d = fc & 63;
    #pragma unroll
    for (int i=0;i<4;i++){
      int s = sbase + wm*64 + i*16 + (lq<<2);
      int b = s >> 11, sq = s & 2047;
      f32x4 v = acc[i][j];
      uint2 pk;
      pk.x = pack2(v.x + bv, v.y + bv);
      pk.y = pack2(v.z + bv, v.w + bv);
      *(uint2*)&out[(((size_t)(b*H_ + h))*DH_ + d)*S_ + sq] = pk;
    }
  }
}

// ---------------------------------------------------------------------------
// Fused attention v4: batch-in-lane, k-tile = 32, all-b128 conflict-free LDS.
//
// K staged PERMUTED: tile t (t=0,1) row x holds global k-row (x>>2)*8+t*4+(x&3),
// so the two QK C-outputs give lane (ln,lq) S-values at k = lq*8 + (t*4+r) —
// 8 CONTIGUOUS k per lane == the 16x16x32 B-operand layout. PV runs at K=32
// (16 MFMA/32k instead of 32), still zero cross-lane exchange.
//
// V staged with d-row PAIRING: LDS row r (128B) = [V[d=r][k32] | V[d=r+32][k32]],
// 16B slots XOR-swizzled by (r&7) via source-side permutation (linear LDS dst,
// global_load_lds). vf read = ds_read_b128, each 8-lane group covers 8 distinct
// slots -> conflict-free (fixes the 50M-conflict 4-way b64 pattern of v3).
// One barrier + vmcnt(8) per 32-k iter.
// ---------------------------------------------------------------------------
#define CS_LOG2 0.18033688011112042f      /* 0.125 * log2(e) */
#define CM_LOG2 -1.4426950408889634e9f    /* -1e9 * log2(e) */

__global__ __launch_bounds__(256, 2) void attn(
    const ushort* __restrict__ Q, const ushort* __restrict__ K,
    const ushort* __restrict__ Vt, const float* __restrict__ mask,
    float* __restrict__ out)
{
  __shared__ __align__(16) ushort Kl[2][8192];   // 16KB/buf: [t][b][x16][8 slots]
  __shared__ __align__(16) ushort Vl[2][8192];   // 16KB/buf: [b][r32][8 slots]

  const int tid = threadIdx.x;
  const int l = tid & 63, w = tid >> 6;
  const int ln = l & 15, lq = l >> 4;
  const int bid = blockIdx.x;
  const int h = bid & 15, qtg = bid >> 4;
  const int q0 = (qtg*4 + w)*16;

  const ushort* Kroot = K  + (size_t)h*S_*DH_;
  const ushort* Vroot = Vt + (size_t)h*DH_*S_;

  // ---- staging maps (4 K-chunks + 4 V-chunks per lane, 16B each) ----
  uint ksrc[4], vsrc[4];
  int kdst[4], vdst[4];
  #pragma unroll
  for (int j=0;j<4;j++){
    int ck = (w*4 + j)*64 + l;               // 0..1023
    { // K: chunk = t*512 + b*128 + x*8 + c'
      int t = ck >> 9, rem = ck & 511, b = rem >> 7, rr = rem & 127;
      int x = rr >> 3, cs = rr & 7;
      int c = cs ^ (x & 7);                  // unswizzled DH chunk
      int krow = (x >> 2)*8 + t*4 + (x & 3); // permuted local k-row
      ksrc[j] = (uint)(b*(H_*S_*DH_) + krow*DH_ + c*8);
      kdst[j] = ck*16;                       // bytes; = inst*1024 + l*16 (linear)
    }
    { // V: chunk = b*256 + r*8 + s'
      int b = ck >> 8, rem = ck & 255, r = rem >> 3, ss = rem & 7;
      int s = ss ^ (r & 7);                  // unswizzled slot
      int d = r + (s >> 2)*32, kc = s & 3;   // paired d-rows, 8-k chunk
      vsrc[j] = (uint)(b*(H_*DH_*S_) + d*S_ + kc*8);
      vdst[j] = ck*16;
    }
  }

  // ---- persistent Q fragments (all 4 batches) ----
  bf16x8 qf[4][2];
  #pragma unroll
  for (int b=0;b<4;b++){
    const ushort* Qb = Q + (((size_t)(b*H_ + h))*S_ + q0 + ln)*DH_;
    #pragma unroll
    for (int ks=0;ks<2;ks++)
      qf[b][ks] = *(const bf16x8*)&Qb[ks*32 + lq*8];
  }

  f32x4 of[4][4];                            // [batch][d-tile]
  #pragma unroll
  for (int b=0;b<4;b++)
    #pragma unroll
    for (int dt=0;dt<4;dt++) of[b][dt] = zero4();

  const float* mrow = mask + (size_t)(q0 + ln)*S_ + lq*8;

  // ---- prologue: stage buf0 (kk=0), mask for kk=0 ----
  #pragma unroll
  for (int j=0;j<4;j++) async16((char*)Kl[0] + kdst[j], Kroot + ksrc[j]);
  #pragma unroll
  for (int j=0;j<4;j++) async16((char*)Vl[0] + vdst[j], Vroot + vsrc[j]);
  __builtin_amdgcn_sched_barrier(0);
  f32x4 mk[2][4];
  #pragma unroll
  for (int t=0;t<2;t++)
    #pragma unroll
    for (int b=0;b<4;b++)
      mk[t][b] = *(const f32x4*)&mrow[(size_t)b*S_*S_ + t*4];
  asm volatile("s_waitcnt vmcnt(8)\n\ts_barrier" ::: "memory");

#define ATTN_ITER(CUR, KKV)                                                     \
  {                                                                             \
    const int kk_ = (KKV);                                                      \
    const int kn_ = (kk_ + 32) & (S_ - 1);                                      \
    /* stage next 32-k tile into buf^1 (8 oldest vmem ops of the iter) */       \
    _Pragma("unroll")                                                           \
    for (int j=0;j<4;j++)                                                       \
      async16((char*)Kl[(CUR)^1] + kdst[j], Kroot + ksrc[j] + (uint)kn_*DH_);   \
    _Pragma("unroll")                                                           \
    for (int j=0;j<4;j++)                                                       \
      async16((char*)Vl[(CUR)^1] + vdst[j], Vroot + vsrc[j] + (uint)kn_);       \
    __builtin_amdgcn_sched_barrier(0);                                          \
    /* QK + softmax per 16-row subtile t */                                     \
    uint2 up[2][4];                                                             \
    _Pragma("unroll")                                                           \
    for (int t_=0;t_<2;t_++){                                                   \
      bf16x8 kf[4][2];                                                          \
      _Pragma("unroll")                                                         \
      for (int b=0;b<4;b++)                                                     \
        _Pragma("unroll")                                                       \
        for (int ks=0;ks<2;ks++)                                                \
          kf[b][ks] = *(const bf16x8*)&Kl[CUR][((t_*4+b)*16 + ln)*64 + (((ks*4+lq) ^ (ln&7)))*8]; \
      f32x4 sacc[4];                                                            \
      __builtin_amdgcn_s_setprio(1);                                            \
      _Pragma("unroll")                                                         \
      for (int b=0;b<4;b++){                                                    \
        f32x4 a_ = __builtin_amdgcn_mfma_f32_16x16x32_bf16(kf[b][0], qf[b][0], zero4(), 0,0,0); \
        sacc[b]  = __builtin_amdgcn_mfma_f32_16x16x32_bf16(kf[b][1], qf[b][1], a_, 0,0,0);      \
      }                                                                         \
      __builtin_amdgcn_s_setprio(0);                                            \
      float pw[4][4];                                                           \
      _Pragma("unroll")                                                         \
      for (int j=0;j<4;j++){                                                    \
        float s0 = __builtin_fmaf(sacc[0][j], CS_LOG2, mk[t_][0][j]*CM_LOG2);   \
        float s1 = __builtin_fmaf(sacc[1][j], CS_LOG2, mk[t_][1][j]*CM_LOG2);   \
        float s2 = __builtin_fmaf(sacc[2][j], CS_LOG2, mk[t_][2][j]*CM_LOG2);   \
        float s3 = __builtin_fmaf(sacc[3][j], CS_LOG2, mk[t_][3][j]*CM_LOG2);   \
        float mx = fmaxf(fmaxf(s0,s1), fmaxf(s2,s3));                           \
        float e0 = exp2_hw(s0-mx), e1 = exp2_hw(s1-mx);                         \
        float e2 = exp2_hw(s2-mx), e3 = exp2_hw(s3-mx);                         \
        float inv = __builtin_amdgcn_rcpf((e0+e1)+(e2+e3));                     \
        pw[0][j]=e0*inv; pw[1][j]=e1*inv; pw[2][j]=e2*inv; pw[3][j]=e3*inv;     \
      }                                                                         \
      _Pragma("unroll")                                                         \
      for (int b=0;b<4;b++){                                                    \
        up[t_][b].x = packtr(pw[b][0], pw[b][1]);                               \
        up[t_][b].y = packtr(pw[b][2], pw[b][3]);                               \
      }                                                                         \
    }                                                                           \
    /* mask prefetch for next iter */                                           \
    _Pragma("unroll")                                                           \
    for (int t_=0;t_<2;t_++)                                                    \
      _Pragma("unroll")                                                         \
      for (int b=0;b<4;b++)                                                     \
        mk[t_][b] = *(const f32x4*)&mrow[(size_t)b*S_*S_ + kn_ + t_*4];         \
    /* PV at K=32: pf[b] holds P at k = lq*8 + e (e = t*4 + r) */               \
    _Pragma("unroll")                                                           \
    for (int b=0;b<4;b++){                                                      \
      uint4 u4; u4.x = up[0][b].x; u4.y = up[0][b].y;                           \
      u4.z = up[1][b].x; u4.w = up[1][b].y;                                     \
      bf16x8 pf = __builtin_bit_cast(bf16x8, u4);                               \
      bf16x8 vf[4];                                                             \
      _Pragma("unroll")                                                         \
      for (int dt=0;dt<4;dt++)                                                  \
        vf[dt] = *(const bf16x8*)&Vl[CUR][(b*32 + (dt&1)*16 + ln)*64 + ((((dt>>1)*4 + lq) ^ (ln&7)))*8]; \
      __builtin_amdgcn_s_setprio(1);                                            \
      _Pragma("unroll")                                                         \
      for (int dt=0;dt<4;dt++)                                                  \
        of[b][dt] = __builtin_amdgcn_mfma_f32_16x16x32_bf16(vf[dt], pf, of[b][dt], 0,0,0); \
      __builtin_amdgcn_s_setprio(0);                                            \
    }                                                                           \
    /* drain my 8 stage loads; leave the 8 mask loads in flight */              \
    asm volatile("s_waitcnt vmcnt(8)\n\ts_barrier" ::: "memory");               \
  }

  #pragma unroll 1
  for (int kk = 0; kk < S_; kk += 64){
    ATTN_ITER(0, kk);
    ATTN_ITER(1, kk+32);
  }
#undef ATTN_ITER

  // ---- epilogue: O[b, q0+ln, h*64 + dt*16 + lq*4 + r] ----
  #pragma unroll
  for (int b=0;b<4;b++){
    float* ob = out + ((size_t)b*S_ + q0 + ln)*DM_ + h*DH_;
    #pragma unroll
    for (int dt=0;dt<4;dt++)
      *(f32x4*)&ob[dt*16 + lq*4] = of[b][dt];
  }
}

// ---------------------------------------------------------------------------
extern "C" void kernel_launch(void* const* d_in, const int* in_sizes, int n_in,
                              void* d_out, int out_size, void* d_ws, size_t ws_size,
                              hipStream_t stream)
{
  const float* xq   = (const float*)d_in[0];
  const float* xk   = (const float*)d_in[1];
  const float* xv   = (const float*)d_in[2];
  const float* mask = (const float*)d_in[3];
  const float* Wq   = (const float*)d_in[4];
  const float* bq   = (const float*)d_in[5];
  const float* Wk   = (const float*)d_in[6];
  const float* bk   = (const float*)d_in[7];
  const float* Wv   = (const float*)d_in[8];
  const float* bv   = (const float*)d_in[9];
  float* out = (float*)d_out;

  char* ws = (char*)d_ws;                      // 70 MB used
  ushort* Wtq = (ushort*)(ws);                 // 2 MB each
  ushort* Wtk = (ushort*)(ws + (2ull<<20));
  ushort* Wtv = (ushort*)(ws + (4ull<<20));
  ushort* Xbq = (ushort*)(ws + (6ull<<20));    // 16 MB each
  ushort* Xbk = (ushort*)(ws + (22ull<<20));
  ushort* Qb  = (ushort*)(ws + (38ull<<20));
  ushort* Kb  = (ushort*)(ws + (54ull<<20));
  ushort* Vtb = Xbq;                           // safe: Xbq consumed by gemm_qk before gemm_v runs

  conv2<<<dim3(4096,2), 256, 0, stream>>>(xq, xk, Xbq, Xbk);
  wtrans3<<<dim3(32,32,3), 256, 0, stream>>>(Wq, Wk, Wv, Wtq, Wtk, Wtv);

  gemm_qk<<<dim3(64,8,2), 256, 0, stream>>>(Xbq, Xbk, Wtq, Wtk, bq, bk, Qb, Kb);
  gemm_v<<<dim3(64,8), 256, 0, stream>>>(xv, Wtv, bv, Vtb);

  attn<<<512, 256, 0, stream>>>(Qb, Kb, Vtb, mask, out);
}